// Round 10
// baseline (224.625 us; speedup 1.0000x reference)
//
#include <hip/hip_runtime.h>

typedef short bf16x8 __attribute__((ext_vector_type(8)));
typedef float f32x4 __attribute__((ext_vector_type(4)));

#define LN_EPS 1e-5f
#define SLOPE 0.2f

__device__ __forceinline__ float bf2f(unsigned short s){
  return __uint_as_float(((unsigned)s) << 16);
}
__device__ __forceinline__ unsigned short f2bf(float f){
  unsigned u = __float_as_uint(f);
  u += 0x7fffu + ((u >> 16) & 1u);   // round-to-nearest-even
  return (unsigned short)(u >> 16);
}

// Verified W image (rounds 1/4/6/7/9, scalar):
// element ((s*4+g)*512 + c)*8 + j  =  W[k = s*32+g*8+j][c]   (c<256: W_l, else W_r)
__global__ void wconv_kernel(const float* __restrict__ Wl,
                             const float* __restrict__ Wr,
                             unsigned short* __restrict__ wbf){
  int idx = blockIdx.x * 256 + threadIdx.x;   // 0..131071
  int j = idx & 7;
  int c = (idx >> 3) & 511;
  int g = (idx >> 12) & 3;
  int s = idx >> 14;
  int k = s * 32 + g * 8 + j;
  float v = (c < 256) ? Wl[k * 256 + c] : Wr[k * 256 + (c - 256)];
  wbf[idx] = f2bf(v);
}

// Register-attention v3 (R9 verified core + mt-split for occupancy):
// acc[4][8] (128 AGPR) was capping occupancy at 2 waves/SIMD (112 VGPR + 128
// AGPR = 240/wave on the unified file). Outer mt loop (2 m-blocks per pass)
// halves the live accumulator to acc[2][8] = 64 AGPR; W frags re-read from L2
// per pass (small, overlappable). Same verified algebra, m -> mt*2+mm.
// NOTE: minwaves/EU >= 4 in __launch_bounds__ MISCOMPILES (R5->R6 test). Keep 2.
template<bool USE_WS>
__global__ __launch_bounds__(256, 2)
void gat_fused(const float* __restrict__ hin, const float* __restrict__ ebias,
               const float* __restrict__ Wl, const float* __restrict__ Wr,
               const float* __restrict__ avec, const float* __restrict__ gmw,
               const float* __restrict__ btw, const unsigned short* __restrict__ wbf,
               float* __restrict__ out){
  __shared__ __align__(16) unsigned short uni[16384];   // h-tile, 32KB
  __shared__ float red1[256], red2[256];                // [row][wave] LN partials
  __shared__ float eb_s[16];

  const int t = threadIdx.x;
  const int lane = t & 63;
  const int w = t >> 6;
  const int b0 = blockIdx.x * 16;
  const int g = lane >> 4;
  const int ln = lane & 15;

  // per-lane constants (registers); edge_bias via LDS broadcast (saves 16 VGPR)
  float av[4], gmr[4], btr[4];
  #pragma unroll
  for (int c = 0; c < 4; ++c){
    av[c]  = avec[w * 64 + c * 16 + ln];
    gmr[c] = gmw [w * 64 + c * 16 + ln];
    btr[c] = btw [w * 64 + c * 16 + ln];
  }
  if (t < 16) eb_s[t] = ebias[t];

  // ---- stage h tile (64 rows x 256 k) f32->bf16, XOR-swizzled (verified R4)
  {
    const float* hb = hin + (size_t)b0 * 1024;
    #pragma unroll
    for (int it = 0; it < 8; ++it){
      int q = it * 256 + t;              // 16B-chunk id, 2048 total
      int row = q >> 5;
      int c = q & 31;
      const float* src = hb + row * 256 + c * 8;
      float4 f0 = *(const float4*)src;
      float4 f1 = *(const float4*)(src + 4);
      bf16x8 v;
      v[0]=(short)f2bf(f0.x); v[1]=(short)f2bf(f0.y); v[2]=(short)f2bf(f0.z); v[3]=(short)f2bf(f0.w);
      v[4]=(short)f2bf(f1.x); v[5]=(short)f2bf(f1.y); v[6]=(short)f2bf(f1.z); v[7]=(short)f2bf(f1.w);
      *(bf16x8*)&uni[row * 256 + ((c ^ (row & 7)) << 3)] = v;
    }
  }
  __syncthreads();

  #pragma unroll 1                       // keep mt iterations separate (reg cap)
  for (int mt = 0; mt < 2; ++mt){
    f32x4 acc[2][8];
    #pragma unroll
    for (int mm = 0; mm < 2; ++mm)
      #pragma unroll
      for (int c = 0; c < 8; ++c)
        acc[mm][c] = (f32x4){0.f, 0.f, 0.f, 0.f};

    // ---- barrier-free K loop for m = mt*2 + mm (verified R4/R9 fragments)
    for (int step = 0; step < 8; ++step){
      bf16x8 af[2];
      #pragma unroll
      for (int mm = 0; mm < 2; ++mm){
        int row = mt * 32 + mm * 16 + ln;      // row&7 == ln&7
        int chunk = step * 4 + g;
        af[mm] = *(const bf16x8*)&uni[row * 256 + ((chunk ^ (ln & 7)) << 3)];
      }
      if constexpr (USE_WS){
        const unsigned short* wp = wbf + (size_t)step * 16384 + (size_t)g * 4096
                                 + (size_t)(w * 64 + ln) * 8;
        bf16x8 ba[4], bb[4];
        #pragma unroll
        for (int c = 0; c < 4; ++c) ba[c] = *(const bf16x8*)(wp + c * 128);   // gl cols
        #pragma unroll
        for (int mm = 0; mm < 2; ++mm)
          #pragma unroll
          for (int c = 0; c < 4; ++c)
            acc[mm][c] = __builtin_amdgcn_mfma_f32_16x16x32_bf16(af[mm], ba[c], acc[mm][c], 0, 0, 0);
        #pragma unroll
        for (int c = 0; c < 4; ++c) bb[c] = *(const bf16x8*)(wp + 2048 + c * 128); // gr cols
        #pragma unroll
        for (int mm = 0; mm < 2; ++mm)
          #pragma unroll
          for (int c = 0; c < 4; ++c)
            acc[mm][c + 4] = __builtin_amdgcn_mfma_f32_16x16x32_bf16(af[mm], bb[c], acc[mm][c + 4], 0, 0, 0);
      } else {
        #pragma unroll
        for (int c = 0; c < 4; ++c){
          int col = w * 64 + c * 16 + ln;
          bf16x8 ba, bb;
          #pragma unroll
          for (int j = 0; j < 8; ++j){
            ba[j] = (short)f2bf(Wl[(step * 32 + g * 8 + j) * 256 + col]);
            bb[j] = (short)f2bf(Wr[(step * 32 + g * 8 + j) * 256 + col]);
          }
          #pragma unroll
          for (int mm = 0; mm < 2; ++mm){
            acc[mm][c]     = __builtin_amdgcn_mfma_f32_16x16x32_bf16(af[mm], ba, acc[mm][c], 0, 0, 0);
            acc[mm][c + 4] = __builtin_amdgcn_mfma_f32_16x16x32_bf16(af[mm], bb, acc[mm][c + 4], 0, 0, 0);
          }
        }
      }
    }

    // ---- attention in registers (R9 verbatim, m -> mt*2+mm); hp stays in f32 regs
    float hp[2][4][4];     // [mm][node i][c-chunk]
    #pragma unroll
    for (int mm = 0; mm < 2; ++mm){
      float e[16];
      #pragma unroll
      for (int q = 0; q < 16; ++q) e[q] = 0.f;
      #pragma unroll
      for (int c = 0; c < 4; ++c){
        f32x4 GL = acc[mm][c];
        f32x4 GR = acc[mm][c + 4];
        #pragma unroll
        for (int i = 0; i < 4; ++i)
          #pragma unroll
          for (int j = 0; j < 4; ++j){
            float x = GL[i] + GR[j];
            x = fmaxf(x, SLOPE * x);      // leaky_relu
            e[i * 4 + j] = fmaf(x, av[c], e[i * 4 + j]);
          }
      }
      #pragma unroll
      for (int mask = 1; mask <= 8; mask <<= 1)
        #pragma unroll
        for (int q = 0; q < 16; ++q)
          e[q] += __shfl_xor(e[q], mask);
      #pragma unroll
      for (int q = 0; q < 16; ++q) e[q] += eb_s[q];
      #pragma unroll
      for (int i = 0; i < 4; ++i){
        float mx = fmaxf(fmaxf(e[i*4+0], e[i*4+1]), fmaxf(e[i*4+2], e[i*4+3]));
        float p0 = __expf(e[i*4+0] - mx);
        float p1 = __expf(e[i*4+1] - mx);
        float p2 = __expf(e[i*4+2] - mx);
        float p3 = __expf(e[i*4+3] - mx);
        float rs = 1.f / (p0 + p1 + p2 + p3);
        e[i*4+0] = p0 * rs; e[i*4+1] = p1 * rs; e[i*4+2] = p2 * rs; e[i*4+3] = p3 * rs;
      }
      #pragma unroll
      for (int i = 0; i < 4; ++i){
        #pragma unroll
        for (int c = 0; c < 4; ++c){
          f32x4 GR = acc[mm][c + 4];
          float v = e[i*4+0] * GR[0];
          v = fmaf(e[i*4+1], GR[1], v);
          v = fmaf(e[i*4+2], GR[2], v);
          v = fmaf(e[i*4+3], GR[3], v);
          hp[mm][i][c] = v;
        }
        float s1 = hp[mm][i][0] + hp[mm][i][1] + hp[mm][i][2] + hp[mm][i][3];
        float s2 = fmaf(hp[mm][i][0], hp[mm][i][0],
                   fmaf(hp[mm][i][1], hp[mm][i][1],
                   fmaf(hp[mm][i][2], hp[mm][i][2], hp[mm][i][3] * hp[mm][i][3])));
        #pragma unroll
        for (int mask = 1; mask <= 8; mask <<= 1){
          s1 += __shfl_xor(s1, mask);
          s2 += __shfl_xor(s2, mask);
        }
        int r = ((mt * 2 + mm) * 4 + g) * 4 + i;   // disjoint ranges per mt
        if (ln == 0){ red1[r * 4 + w] = s1; red2[r * 4 + w] = s2; }
      }
    }
    __syncthreads();

    // ---- epilogue for this mt: combine head partials, normalize, store
    #pragma unroll
    for (int mm = 0; mm < 2; ++mm)
      #pragma unroll
      for (int i = 0; i < 4; ++i){
        int r = ((mt * 2 + mm) * 4 + g) * 4 + i;
        float4 v1 = *(const float4*)&red1[r * 4];
        float4 v2 = *(const float4*)&red2[r * 4];
        float s1 = (v1.x + v1.y) + (v1.z + v1.w);
        float s2 = (v2.x + v2.y) + (v2.z + v2.w);
        float mu = s1 * (1.f / 256.f);
        float var = s2 * (1.f / 256.f) - mu * mu;
        float inv = rsqrtf(var + LN_EPS);
        float* op = out + ((size_t)b0 * 4 + r) * 256 + w * 64 + ln;
        #pragma unroll
        for (int c = 0; c < 4; ++c)
          op[c * 16] = fmaf((hp[mm][i][c] - mu) * inv, gmr[c], btr[c]);
      }
  }
}

extern "C" void kernel_launch(void* const* d_in, const int* in_sizes, int n_in,
                              void* d_out, int out_size, void* d_ws, size_t ws_size,
                              hipStream_t stream){
  const float* h  = (const float*)d_in[0];
  const float* eb = (const float*)d_in[1];
  const float* Wl = (const float*)d_in[2];
  const float* Wr = (const float*)d_in[3];
  const float* a  = (const float*)d_in[4];
  const float* gm = (const float*)d_in[5];
  const float* bt = (const float*)d_in[6];
  float* out = (float*)d_out;
  (void)n_in; (void)out_size;

  int B = in_sizes[0] / 1024;        // (B, 4, 256) f32
  int nblk = B / 16;

  if (ws_size >= 262144){
    unsigned short* wbf = (unsigned short*)d_ws;
    wconv_kernel<<<512, 256, 0, stream>>>(Wl, Wr, wbf);
    gat_fused<true><<<nblk, 256, 0, stream>>>(h, eb, Wl, Wr, a, gm, bt, wbf, out);
  } else {
    gat_fused<false><<<nblk, 256, 0, stream>>>(h, eb, Wl, Wr, a, gm, bt, nullptr, out);
  }
}

// Round 11
// 96.638 us; speedup vs baseline: 2.3244x; 2.3244x over previous
//
#include <hip/hip_runtime.h>

typedef short bf16x8 __attribute__((ext_vector_type(8)));
typedef float f32x4 __attribute__((ext_vector_type(4)));

#define LN_EPS 1e-5f
#define SLOPE 0.2f

__device__ __forceinline__ float bf2f(unsigned short s){
  return __uint_as_float(((unsigned)s) << 16);
}
__device__ __forceinline__ unsigned short f2bf(float f){
  unsigned u = __float_as_uint(f);
  u += 0x7fffu + ((u >> 16) & 1u);   // round-to-nearest-even
  return (unsigned short)(u >> 16);
}

// Verified W image (rounds 1/4/6/7/9, scalar):
// element ((s*4+g)*512 + c)*8 + j  =  W[k = s*32+g*8+j][c]   (c<256: W_l, else W_r)
__global__ void wconv_kernel(const float* __restrict__ Wl,
                             const float* __restrict__ Wr,
                             unsigned short* __restrict__ wbf){
  int idx = blockIdx.x * 256 + threadIdx.x;   // 0..131071
  int j = idx & 7;
  int c = (idx >> 3) & 511;
  int g = (idx >> 12) & 3;
  int s = idx >> 14;
  int k = s * 32 + g * 8 + j;
  float v = (c < 256) ? Wl[k * 256 + c] : Wr[k * 256 + (c - 256)];
  wbf[idx] = f2bf(v);
}

// Register-attention (R9-verified algebra), 8 batches/block for occupancy:
// per-wave live state halves (acc[2][8]=64 AGPR, hp 32, e 16) -> ~150-160
// regs/wave -> 3 waves/SIMD (vs R9's 240 -> 2). Straight-line, no outer loop,
// no forced unroll caps (R10's mt-split spilled to scratch: FETCH/WRITE +260MB).
// NOTE: minwaves/EU >= 4 in __launch_bounds__ MISCOMPILES (R5->R6 test). Keep 2.
template<bool USE_WS>
__global__ __launch_bounds__(256, 2)
void gat_fused(const float* __restrict__ hin, const float* __restrict__ ebias,
               const float* __restrict__ Wl, const float* __restrict__ Wr,
               const float* __restrict__ avec, const float* __restrict__ gmw,
               const float* __restrict__ btw, const unsigned short* __restrict__ wbf,
               float* __restrict__ out){
  __shared__ __align__(16) unsigned short uni[8192];    // h-tile [32][256] bf16, 16KB
  __shared__ float red1[128], red2[128];                // [row][wave] LN partials
  __shared__ float eb_s[16];

  const int t = threadIdx.x;
  const int lane = t & 63;
  const int w = t >> 6;
  const int b0 = blockIdx.x * 8;
  const int g = lane >> 4;
  const int ln = lane & 15;

  // per-lane constants (registers); edge_bias via LDS (saves 16 VGPR)
  float av[4], gmr[4], btr[4];
  #pragma unroll
  for (int c = 0; c < 4; ++c){
    av[c]  = avec[w * 64 + c * 16 + ln];
    gmr[c] = gmw [w * 64 + c * 16 + ln];
    btr[c] = btw [w * 64 + c * 16 + ln];
  }
  if (t < 16) eb_s[t] = ebias[t];

  // ---- stage h tile (32 rows x 256 k) f32->bf16, XOR-swizzled (verified R4)
  {
    const float* hb = hin + (size_t)b0 * 1024;
    #pragma unroll
    for (int it = 0; it < 4; ++it){
      int q = it * 256 + t;              // 16B-chunk id, 1024 total
      int row = q >> 5;
      int c = q & 31;
      const float* src = hb + row * 256 + c * 8;
      float4 f0 = *(const float4*)src;
      float4 f1 = *(const float4*)(src + 4);
      bf16x8 v;
      v[0]=(short)f2bf(f0.x); v[1]=(short)f2bf(f0.y); v[2]=(short)f2bf(f0.z); v[3]=(short)f2bf(f0.w);
      v[4]=(short)f2bf(f1.x); v[5]=(short)f2bf(f1.y); v[6]=(short)f2bf(f1.z); v[7]=(short)f2bf(f1.w);
      *(bf16x8*)&uni[row * 256 + ((c ^ (row & 7)) << 3)] = v;
    }
  }
  __syncthreads();

  f32x4 acc[2][8];
  #pragma unroll
  for (int m = 0; m < 2; ++m)
    #pragma unroll
    for (int c = 0; c < 8; ++c)
      acc[m][c] = (f32x4){0.f, 0.f, 0.f, 0.f};

  // ---- barrier-free K loop: A = h frags from LDS, B = W frags from L2 (verified R4)
  for (int step = 0; step < 8; ++step){
    bf16x8 af[2], bfr[8];
    #pragma unroll
    for (int m = 0; m < 2; ++m){
      int row = m * 16 + ln;
      int chunk = step * 4 + g;
      af[m] = *(const bf16x8*)&uni[row * 256 + ((chunk ^ (row & 7)) << 3)];
    }
    if constexpr (USE_WS){
      const unsigned short* wp = wbf + (size_t)step * 16384 + (size_t)g * 4096
                               + (size_t)(w * 64 + ln) * 8;
      #pragma unroll
      for (int c = 0; c < 4; ++c){
        bfr[c]     = *(const bf16x8*)(wp + c * 128);          // gl col w*64+c*16+ln
        bfr[c + 4] = *(const bf16x8*)(wp + 2048 + c * 128);   // gr col 256+w*64+c*16+ln
      }
    } else {
      #pragma unroll
      for (int c = 0; c < 4; ++c){
        int col = w * 64 + c * 16 + ln;
        #pragma unroll
        for (int j = 0; j < 8; ++j){
          bfr[c][j]     = (short)f2bf(Wl[(step * 32 + g * 8 + j) * 256 + col]);
          bfr[c + 4][j] = (short)f2bf(Wr[(step * 32 + g * 8 + j) * 256 + col]);
        }
      }
    }
    #pragma unroll
    for (int m = 0; m < 2; ++m)
      #pragma unroll
      for (int c = 0; c < 8; ++c)
        acc[m][c] = __builtin_amdgcn_mfma_f32_16x16x32_bf16(af[m], bfr[c], acc[m][c], 0, 0, 0);
  }
  __syncthreads();        // all LDS h-tile reads done; uni never touched again

  // ---- attention fully in registers (R9 verbatim, m range 0..1)
  float hp[2][4][4];      // [m][node i][c-chunk]
  #pragma unroll
  for (int m = 0; m < 2; ++m){
    float e[16];
    #pragma unroll
    for (int q = 0; q < 16; ++q) e[q] = 0.f;
    #pragma unroll
    for (int c = 0; c < 4; ++c){
      f32x4 GL = acc[m][c];
      f32x4 GR = acc[m][c + 4];
      #pragma unroll
      for (int i = 0; i < 4; ++i)
        #pragma unroll
        for (int j = 0; j < 4; ++j){
          float x = GL[i] + GR[j];
          x = fmaxf(x, SLOPE * x);        // leaky_relu
          e[i * 4 + j] = fmaf(x, av[c], e[i * 4 + j]);
        }
    }
    #pragma unroll
    for (int mask = 1; mask <= 8; mask <<= 1)
      #pragma unroll
      for (int q = 0; q < 16; ++q)
        e[q] += __shfl_xor(e[q], mask);
    #pragma unroll
    for (int q = 0; q < 16; ++q) e[q] += eb_s[q];
    #pragma unroll
    for (int i = 0; i < 4; ++i){
      float mx = fmaxf(fmaxf(e[i*4+0], e[i*4+1]), fmaxf(e[i*4+2], e[i*4+3]));
      float p0 = __expf(e[i*4+0] - mx);
      float p1 = __expf(e[i*4+1] - mx);
      float p2 = __expf(e[i*4+2] - mx);
      float p3 = __expf(e[i*4+3] - mx);
      float rs = 1.f / (p0 + p1 + p2 + p3);
      e[i*4+0] = p0 * rs; e[i*4+1] = p1 * rs; e[i*4+2] = p2 * rs; e[i*4+3] = p3 * rs;
    }
    #pragma unroll
    for (int i = 0; i < 4; ++i){
      #pragma unroll
      for (int c = 0; c < 4; ++c){
        f32x4 GR = acc[m][c + 4];
        float v = e[i*4+0] * GR[0];
        v = fmaf(e[i*4+1], GR[1], v);
        v = fmaf(e[i*4+2], GR[2], v);
        v = fmaf(e[i*4+3], GR[3], v);
        hp[m][i][c] = v;
      }
      float s1 = hp[m][i][0] + hp[m][i][1] + hp[m][i][2] + hp[m][i][3];
      float s2 = fmaf(hp[m][i][0], hp[m][i][0],
                 fmaf(hp[m][i][1], hp[m][i][1],
                 fmaf(hp[m][i][2], hp[m][i][2], hp[m][i][3] * hp[m][i][3])));
      #pragma unroll
      for (int mask = 1; mask <= 8; mask <<= 1){
        s1 += __shfl_xor(s1, mask);
        s2 += __shfl_xor(s2, mask);
      }
      int r = (m * 4 + g) * 4 + i;        // 0..31
      if (ln == 0){ red1[r * 4 + w] = s1; red2[r * 4 + w] = s2; }
    }
  }
  __syncthreads();

  // ---- epilogue: combine 4 head-partials, normalize own hp, store
  #pragma unroll
  for (int m = 0; m < 2; ++m)
    #pragma unroll
    for (int i = 0; i < 4; ++i){
      int r = (m * 4 + g) * 4 + i;
      float4 v1 = *(const float4*)&red1[r * 4];
      float4 v2 = *(const float4*)&red2[r * 4];
      float s1 = (v1.x + v1.y) + (v1.z + v1.w);
      float s2 = (v2.x + v2.y) + (v2.z + v2.w);
      float mu = s1 * (1.f / 256.f);
      float var = s2 * (1.f / 256.f) - mu * mu;
      float inv = rsqrtf(var + LN_EPS);
      float* op = out + ((size_t)b0 * 4 + r) * 256 + w * 64 + ln;
      #pragma unroll
      for (int c = 0; c < 4; ++c)
        op[c * 16] = fmaf((hp[m][i][c] - mu) * inv, gmr[c], btr[c]);
    }
}

extern "C" void kernel_launch(void* const* d_in, const int* in_sizes, int n_in,
                              void* d_out, int out_size, void* d_ws, size_t ws_size,
                              hipStream_t stream){
  const float* h  = (const float*)d_in[0];
  const float* eb = (const float*)d_in[1];
  const float* Wl = (const float*)d_in[2];
  const float* Wr = (const float*)d_in[3];
  const float* a  = (const float*)d_in[4];
  const float* gm = (const float*)d_in[5];
  const float* bt = (const float*)d_in[6];
  float* out = (float*)d_out;
  (void)n_in; (void)out_size;

  int B = in_sizes[0] / 1024;        // (B, 4, 256) f32
  int nblk = B / 8;

  if (ws_size >= 262144){
    unsigned short* wbf = (unsigned short*)d_ws;
    wconv_kernel<<<512, 256, 0, stream>>>(Wl, Wr, wbf);
    gat_fused<true><<<nblk, 256, 0, stream>>>(h, eb, Wl, Wr, a, gm, bt, wbf, out);
  } else {
    gat_fused<false><<<nblk, 256, 0, stream>>>(h, eb, Wl, Wr, a, gm, bt, nullptr, out);
  }
}